// Round 2
// baseline (969.312 us; speedup 1.0000x reference)
//
#include <hip/hip_runtime.h>
#include <hip/hip_bf16.h>

#define IN_CH 602
#define HID 256
#define N0C 256000
#define N1C 10240
#define N2C 1024
#define E1C 256000
#define E2C 10240
#define K1 1216   // 2*602=1204 padded to multiple of 32
#define K2 512

typedef __bf16 bf16x8 __attribute__((ext_vector_type(8)));
typedef float f32x4 __attribute__((ext_vector_type(4)));
typedef unsigned short u16;

// ---------------- CSR build ----------------

__global__ void hist_kernel(const int* __restrict__ dst, int* __restrict__ cnt, int E) {
    int i = blockIdx.x * blockDim.x + threadIdx.x;
    if (i < E) atomicAdd(&cnt[dst[i]], 1);
}

// single block, 256 threads; n divisible by 256
__global__ void scan_kernel(const int* __restrict__ cnt, int* __restrict__ offs,
                            int* __restrict__ cursor, int n) {
    __shared__ int part[256];
    int tid = threadIdx.x;
    int chunk = n >> 8;
    int lo = tid * chunk;
    int s = 0;
    for (int i = 0; i < chunk; i++) s += cnt[lo + i];
    part[tid] = s;
    __syncthreads();
    for (int d = 1; d < 256; d <<= 1) {
        int v = (tid >= d) ? part[tid - d] : 0;
        __syncthreads();
        part[tid] += v;
        __syncthreads();
    }
    int run = part[tid] - s;  // exclusive prefix
    for (int i = 0; i < chunk; i++) {
        offs[lo + i] = run;
        cursor[lo + i] = run;
        run += cnt[lo + i];
    }
}

__global__ void fill_kernel(const int* __restrict__ src, const int* __restrict__ dst,
                            int* __restrict__ cursor, int* __restrict__ eidx, int E) {
    int i = blockIdx.x * blockDim.x + threadIdx.x;
    if (i < E) {
        int p = atomicAdd(&cursor[dst[i]], 1);
        eidx[p] = src[i];
    }
}

// ---------------- weight prep: Bt[n][k] = [Wl;Wr](k,n), bf16, zero-padded ----------------

__global__ void build_bt_kernel(const float* __restrict__ Wl, const float* __restrict__ Wr,
                                __hip_bfloat16* __restrict__ Bt, int Kin, int Kpad) {
    int idx = blockIdx.x * blockDim.x + threadIdx.x;
    int total = HID * Kpad;
    if (idx >= total) return;
    int n = idx / Kpad, k = idx - n * Kpad;
    float v = 0.f;
    if (k < Kin)            v = Wl[k * HID + n];
    else if (k < 2 * Kin)   v = Wr[(k - Kin) * HID + n];
    Bt[(size_t)n * Kpad + k] = __float2bfloat16(v);
}

// ---------------- layer-1 aggregation: A1 row = [mean_agg(602) | x_root(602) | 0(12)] bf16 ----------------

__global__ void agg1_kernel(const float* __restrict__ x, const int* __restrict__ cnt,
                            const int* __restrict__ offs, const int* __restrict__ eidx,
                            __hip_bfloat16* __restrict__ A1) {
    int t = blockIdx.x;
    int tid = threadIdx.x;
    int deg = cnt[t];
    int base = offs[t];
    float a0 = 0.f, a1 = 0.f, a2 = 0.f;
    for (int i = 0; i < deg; i++) {
        const float* row = x + (size_t)eidx[base + i] * IN_CH;
        a0 += row[tid];
        if (tid < IN_CH - 256) a1 += row[tid + 256];
        if (tid < IN_CH - 512) a2 += row[tid + 512];
    }
    float inv = 1.0f / (float)(deg > 0 ? deg : 1);
    __hip_bfloat16* d = A1 + (size_t)t * K1;
    d[tid] = __float2bfloat16(a0 * inv);
    if (tid < IN_CH - 256) d[tid + 256] = __float2bfloat16(a1 * inv);
    if (tid < IN_CH - 512) d[tid + 512] = __float2bfloat16(a2 * inv);
    const float* xr = x + (size_t)t * IN_CH;
    d[IN_CH + tid] = __float2bfloat16(xr[tid]);
    if (tid < IN_CH - 256) d[IN_CH + tid + 256] = __float2bfloat16(xr[tid + 256]);
    if (tid < IN_CH - 512) d[IN_CH + tid + 512] = __float2bfloat16(xr[tid + 512]);
    if (tid < K1 - 2 * IN_CH) d[2 * IN_CH + tid] = __float2bfloat16(0.f);
}

// ---------------- layer-2 aggregation: A2 row = [mean_agg(256) | h_root(256)] bf16 ----------------

__global__ void agg2_kernel(const __hip_bfloat16* __restrict__ h, const int* __restrict__ cnt,
                            const int* __restrict__ offs, const int* __restrict__ eidx,
                            __hip_bfloat16* __restrict__ A2) {
    int t = blockIdx.x, tid = threadIdx.x;
    int deg = cnt[t], base = offs[t];
    float acc = 0.f;
    for (int i = 0; i < deg; i++)
        acc += __bfloat162float(h[(size_t)eidx[base + i] * HID + tid]);
    float inv = 1.0f / (float)(deg > 0 ? deg : 1);
    A2[(size_t)t * K2 + tid] = __float2bfloat16(acc * inv);
    A2[(size_t)t * K2 + HID + tid] = h[(size_t)t * HID + tid];
}

// ---------------- bf16 MFMA GEMM: C[M,256] = A[M,K] * Bt[256,K]^T + bias ----------------
// 128x128 block tile, 4 waves in 2x2, each wave 64x64 via 4x4 grid of 16x16x32 MFMAs.
// Staging: 256 threads x 2 iters x uint4(8 u16) = 4096 u16 = full 128x32 tile.

template <int K, bool RELU, bool OUT_BF16>
__global__ __launch_bounds__(256) void gemm_kernel(const __hip_bfloat16* __restrict__ A,
                                                   const __hip_bfloat16* __restrict__ Bt,
                                                   const float* __restrict__ bias,
                                                   void* __restrict__ Cout) {
    __shared__ __align__(16) u16 As[128 * 40];  // stride 40 (pad 32->40: 20-bank step, ~2-way only)
    __shared__ __align__(16) u16 Bs[128 * 40];
    int tid = threadIdx.x;
    int m0 = blockIdx.x * 128;
    int n0 = blockIdx.y * 128;
    int wave = tid >> 6, lane = tid & 63;
    int wm = (wave & 1) * 64, wn = (wave >> 1) * 64;
    int lm = lane & 15, quad = lane >> 4;
    int k8 = quad * 8;
    int sr = tid >> 2;          // staging row 0..63
    int sc = (tid & 3) * 8;     // staging column octet 0,8,16,24
    const u16* Au = (const u16*)A;
    const u16* Bu = (const u16*)Bt;

    f32x4 acc[4][4];
#pragma unroll
    for (int i = 0; i < 4; i++)
#pragma unroll
        for (int j = 0; j < 4; j++) acc[i][j] = (f32x4){0.f, 0.f, 0.f, 0.f};

    for (int kt = 0; kt < K; kt += 32) {
#pragma unroll
        for (int hh = 0; hh < 2; hh++) {
            int r = sr + 64 * hh;
            *(uint4*)&As[r * 40 + sc] = *(const uint4*)&Au[(size_t)(m0 + r) * K + kt + sc];
            *(uint4*)&Bs[r * 40 + sc] = *(const uint4*)&Bu[(size_t)(n0 + r) * K + kt + sc];
        }
        __syncthreads();
        bf16x8 a[4], b[4];
#pragma unroll
        for (int i = 0; i < 4; i++) a[i] = *(const bf16x8*)&As[(wm + i * 16 + lm) * 40 + k8];
#pragma unroll
        for (int j = 0; j < 4; j++) b[j] = *(const bf16x8*)&Bs[(wn + j * 16 + lm) * 40 + k8];
#pragma unroll
        for (int i = 0; i < 4; i++)
#pragma unroll
            for (int j = 0; j < 4; j++)
                acc[i][j] = __builtin_amdgcn_mfma_f32_16x16x32_bf16(a[i], b[j], acc[i][j], 0, 0, 0);
        __syncthreads();
    }

#pragma unroll
    for (int i = 0; i < 4; i++) {
#pragma unroll
        for (int j = 0; j < 4; j++) {
            int n = n0 + wn + j * 16 + lm;
            float bv = bias[n];
#pragma unroll
            for (int r = 0; r < 4; r++) {
                int m = m0 + wm + i * 16 + quad * 4 + r;
                float v = acc[i][j][r] + bv;
                if (RELU) v = fmaxf(v, 0.f);
                if (OUT_BF16)
                    ((__hip_bfloat16*)Cout)[(size_t)m * HID + n] = __float2bfloat16(v);
                else
                    ((float*)Cout)[(size_t)m * HID + n] = v;
            }
        }
    }
}

// ---------------- launch ----------------

extern "C" void kernel_launch(void* const* d_in, const int* in_sizes, int n_in,
                              void* d_out, int out_size, void* d_ws, size_t ws_size,
                              hipStream_t stream) {
    const float* x   = (const float*)d_in[0];
    const int* src1  = (const int*)d_in[1];
    const int* dst1  = (const int*)d_in[2];
    const int* src2  = (const int*)d_in[3];
    const int* dst2  = (const int*)d_in[4];
    const float* W1l = (const float*)d_in[5];
    const float* b1  = (const float*)d_in[6];
    const float* W1r = (const float*)d_in[7];
    const float* W2l = (const float*)d_in[8];
    const float* b2  = (const float*)d_in[9];
    const float* W2r = (const float*)d_in[10];

    char* ws = (char*)d_ws;
    size_t off = 0;
    auto carve = [&](size_t bytes) -> char* {
        char* p = ws + off;
        off += (bytes + 255) & ~(size_t)255;
        return p;
    };
    __hip_bfloat16* A1  = (__hip_bfloat16*)carve((size_t)N1C * K1 * 2);
    __hip_bfloat16* Bt1 = (__hip_bfloat16*)carve((size_t)HID * K1 * 2);
    __hip_bfloat16* h   = (__hip_bfloat16*)carve((size_t)N1C * HID * 2);
    __hip_bfloat16* A2  = (__hip_bfloat16*)carve((size_t)N2C * K2 * 2);
    __hip_bfloat16* Bt2 = (__hip_bfloat16*)carve((size_t)HID * K2 * 2);
    int* cnt1  = (int*)carve(N1C * 4);
    int* offs1 = (int*)carve(N1C * 4);
    int* cur1  = (int*)carve(N1C * 4);
    int* eidx1 = (int*)carve((size_t)E1C * 4);
    int* cnt2  = (int*)carve(N2C * 4);
    int* offs2 = (int*)carve(N2C * 4);
    int* cur2  = (int*)carve(N2C * 4);
    int* eidx2 = (int*)carve((size_t)E2C * 4);

    hipMemsetAsync(cnt1, 0, N1C * 4, stream);
    hipMemsetAsync(cnt2, 0, N2C * 4, stream);
    hist_kernel<<<(E1C + 255) / 256, 256, 0, stream>>>(dst1, cnt1, E1C);
    hist_kernel<<<(E2C + 255) / 256, 256, 0, stream>>>(dst2, cnt2, E2C);
    scan_kernel<<<1, 256, 0, stream>>>(cnt1, offs1, cur1, N1C);
    scan_kernel<<<1, 256, 0, stream>>>(cnt2, offs2, cur2, N2C);
    fill_kernel<<<(E1C + 255) / 256, 256, 0, stream>>>(src1, dst1, cur1, eidx1, E1C);
    fill_kernel<<<(E2C + 255) / 256, 256, 0, stream>>>(src2, dst2, cur2, eidx2, E2C);
    build_bt_kernel<<<(HID * K1 + 255) / 256, 256, 0, stream>>>(W1l, W1r, Bt1, IN_CH, K1);
    build_bt_kernel<<<(HID * K2 + 255) / 256, 256, 0, stream>>>(W2l, W2r, Bt2, HID, K2);
    agg1_kernel<<<N1C, 256, 0, stream>>>(x, cnt1, offs1, eidx1, A1);
    gemm_kernel<K1, true, true><<<dim3(N1C / 128, 2), 256, 0, stream>>>(A1, Bt1, b1, h);
    agg2_kernel<<<N2C, 256, 0, stream>>>(h, cnt2, offs2, eidx2, A2);
    gemm_kernel<K2, false, false><<<dim3(N2C / 128, 2), 256, 0, stream>>>(A2, Bt2, b2, d_out);
}

// Round 3
// 894.612 us; speedup vs baseline: 1.0835x; 1.0835x over previous
//
#include <hip/hip_runtime.h>
#include <hip/hip_bf16.h>

#define IN_CH 602
#define HID 256
#define N0C 256000
#define N1C 10240
#define N2C 1024
#define E1C 256000
#define E2C 10240
#define K1 1216   // 2*602=1204 padded to multiple of 32
#define K2 512

typedef __bf16 bf16x8 __attribute__((ext_vector_type(8)));
typedef float f32x4 __attribute__((ext_vector_type(4)));
typedef unsigned short u16;
typedef unsigned int u32;

static __device__ __forceinline__ u32 pack_bf16(float a, float b) {
    __hip_bfloat16 lo = __float2bfloat16(a), hi = __float2bfloat16(b);
    u16 ul = *(u16*)&lo, uh = *(u16*)&hi;
    return (u32)ul | ((u32)uh << 16);
}

// ---------------- CSR build (fused for both levels) ----------------

__global__ void zero_cnt_kernel(int* __restrict__ cnt1, int* __restrict__ cnt2) {
    int i = blockIdx.x * blockDim.x + threadIdx.x;
    if (i < N1C) cnt1[i] = 0;
    else if (i < N1C + N2C) cnt2[i - N1C] = 0;
}

__global__ void hist_kernel(const int* __restrict__ dst1, int* __restrict__ cnt1,
                            const int* __restrict__ dst2, int* __restrict__ cnt2) {
    int i = blockIdx.x * blockDim.x + threadIdx.x;
    if (i < E1C) atomicAdd(&cnt1[dst1[i]], 1);
    else if (i < E1C + E2C) atomicAdd(&cnt2[dst2[i - E1C]], 1);
}

// 2 blocks, 256 threads; block 0 -> level 1, block 1 -> level 2
__global__ void scan_kernel(const int* __restrict__ cnt1, int* __restrict__ offs1, int* __restrict__ cur1,
                            const int* __restrict__ cnt2, int* __restrict__ offs2, int* __restrict__ cur2) {
    const int* cnt = blockIdx.x ? cnt2 : cnt1;
    int* offs = blockIdx.x ? offs2 : offs1;
    int* cursor = blockIdx.x ? cur2 : cur1;
    int n = blockIdx.x ? N2C : N1C;
    __shared__ int part[256];
    int tid = threadIdx.x;
    int chunk = n >> 8;
    int lo = tid * chunk;
    int s = 0;
    for (int i = 0; i < chunk; i++) s += cnt[lo + i];
    part[tid] = s;
    __syncthreads();
    for (int d = 1; d < 256; d <<= 1) {
        int v = (tid >= d) ? part[tid - d] : 0;
        __syncthreads();
        part[tid] += v;
        __syncthreads();
    }
    int run = part[tid] - s;  // exclusive prefix
    for (int i = 0; i < chunk; i++) {
        offs[lo + i] = run;
        cursor[lo + i] = run;
        run += cnt[lo + i];
    }
}

__global__ void fill_kernel(const int* __restrict__ src1, const int* __restrict__ dst1,
                            int* __restrict__ cur1, int* __restrict__ eidx1,
                            const int* __restrict__ src2, const int* __restrict__ dst2,
                            int* __restrict__ cur2, int* __restrict__ eidx2) {
    int i = blockIdx.x * blockDim.x + threadIdx.x;
    if (i < E1C) {
        int p = atomicAdd(&cur1[dst1[i]], 1);
        eidx1[p] = src1[i];
    } else if (i < E1C + E2C) {
        int j = i - E1C;
        int p = atomicAdd(&cur2[dst2[j]], 1);
        eidx2[p] = src2[j];
    }
}

// ---------------- weight prep (both layers): Bt[n][k] = [Wl;Wr](k,n), bf16, zero-padded ----------------

__global__ void build_bt_kernel(const float* __restrict__ W1l, const float* __restrict__ W1r,
                                __hip_bfloat16* __restrict__ Bt1,
                                const float* __restrict__ W2l, const float* __restrict__ W2r,
                                __hip_bfloat16* __restrict__ Bt2) {
    int idx = blockIdx.x * blockDim.x + threadIdx.x;
    const int total1 = HID * K1;
    const float *Wl, *Wr;
    __hip_bfloat16* Bt;
    int Kin, Kpad;
    if (idx < total1) {
        Wl = W1l; Wr = W1r; Bt = Bt1; Kin = IN_CH; Kpad = K1;
    } else {
        idx -= total1;
        if (idx >= HID * K2) return;
        Wl = W2l; Wr = W2r; Bt = Bt2; Kin = HID; Kpad = K2;
    }
    int n = idx / Kpad, k = idx - n * Kpad;
    float v = 0.f;
    if (k < Kin)            v = Wl[k * HID + n];
    else if (k < 2 * Kin)   v = Wr[(k - Kin) * HID + n];
    Bt[(size_t)n * Kpad + k] = __float2bfloat16(v);
}

// ---------------- layer-1 aggregation ----------------
// A1 row (bf16): [0..601]=mean_agg, [602..1203]=x_root, [1204..1215]=0
// float2 view of a 602-float row: 301 float2; thread t covers j=t and j=t+256 (t<45).

__global__ __launch_bounds__(256) void agg1_kernel(const float* __restrict__ x,
                                                   const int* __restrict__ cnt,
                                                   const int* __restrict__ offs,
                                                   const int* __restrict__ eidx,
                                                   u16* __restrict__ A1) {
    __shared__ int nbr[256];
    int t = blockIdx.x, tid = threadIdx.x;
    int deg = cnt[t], base = offs[t];
    const bool has2 = tid < (301 - 256);  // 45 threads carry the second float2
    float2 s0 = {0.f, 0.f}, s1 = {0.f, 0.f};

    for (int c0 = 0; c0 < deg; c0 += 256) {
        int n = deg - c0;
        if (n > 256) n = 256;
        __syncthreads();
        if (tid < n) nbr[tid] = eidx[base + c0 + tid];
        __syncthreads();
        int i = 0;
        for (; i + 4 <= n; i += 4) {
            const float2* r0 = (const float2*)(x + (size_t)nbr[i + 0] * IN_CH);
            const float2* r1 = (const float2*)(x + (size_t)nbr[i + 1] * IN_CH);
            const float2* r2 = (const float2*)(x + (size_t)nbr[i + 2] * IN_CH);
            const float2* r3 = (const float2*)(x + (size_t)nbr[i + 3] * IN_CH);
            float2 v0 = r0[tid], v1 = r1[tid], v2 = r2[tid], v3 = r3[tid];
            float2 w0, w1, w2, w3;
            if (has2) {
                w0 = r0[tid + 256]; w1 = r1[tid + 256];
                w2 = r2[tid + 256]; w3 = r3[tid + 256];
            }
            s0.x += v0.x + v1.x; s0.y += v0.y + v1.y;
            s0.x += v2.x + v3.x; s0.y += v2.y + v3.y;
            if (has2) {
                s1.x += w0.x + w1.x; s1.y += w0.y + w1.y;
                s1.x += w2.x + w3.x; s1.y += w2.y + w3.y;
            }
        }
        for (; i < n; i++) {
            const float2* r0 = (const float2*)(x + (size_t)nbr[i] * IN_CH);
            float2 v0 = r0[tid];
            s0.x += v0.x; s0.y += v0.y;
            if (has2) {
                float2 w0 = r0[tid + 256];
                s1.x += w0.x; s1.y += w0.y;
            }
        }
    }

    float inv = 1.0f / (float)(deg > 0 ? deg : 1);
    u16* d = A1 + (size_t)t * K1;
    // agg part: float2 j -> bf16 elements 2j,2j+1 (u32-aligned pair stores)
    *(u32*)&d[2 * tid] = pack_bf16(s0.x * inv, s0.y * inv);
    if (has2) *(u32*)&d[2 * (tid + 256)] = pack_bf16(s1.x * inv, s1.y * inv);
    // root part
    const float2* xr = (const float2*)(x + (size_t)t * IN_CH);
    float2 v = xr[tid];
    *(u32*)&d[602 + 2 * tid] = pack_bf16(v.x, v.y);
    if (has2) {
        float2 w = xr[tid + 256];
        *(u32*)&d[602 + 2 * (tid + 256)] = pack_bf16(w.x, w.y);
    }
    // pad 1204..1215
    if (tid < 6) *(u32*)&d[1204 + 2 * tid] = 0u;
}

// ---------------- layer-2 aggregation: A2 row = [mean_agg(256) | h_root(256)] bf16 ----------------

__global__ void agg2_kernel(const __hip_bfloat16* __restrict__ h, const int* __restrict__ cnt,
                            const int* __restrict__ offs, const int* __restrict__ eidx,
                            __hip_bfloat16* __restrict__ A2) {
    int t = blockIdx.x, tid = threadIdx.x;
    int deg = cnt[t], base = offs[t];
    float acc = 0.f;
    for (int i = 0; i < deg; i++)
        acc += __bfloat162float(h[(size_t)eidx[base + i] * HID + tid]);
    float inv = 1.0f / (float)(deg > 0 ? deg : 1);
    A2[(size_t)t * K2 + tid] = __float2bfloat16(acc * inv);
    A2[(size_t)t * K2 + HID + tid] = h[(size_t)t * HID + tid];
}

// ---------------- bf16 MFMA GEMM: C[M,256] = A[M,K] * Bt[256,K]^T + bias ----------------
// 128x128 block tile, 4 waves in 2x2, each wave 64x64 via 4x4 grid of 16x16x32 MFMAs.
// Register-prefetch double buffer: tile k+1 global loads issued while tile k computes.

template <int K, bool RELU, bool OUT_BF16>
__global__ __launch_bounds__(256) void gemm_kernel(const __hip_bfloat16* __restrict__ A,
                                                   const __hip_bfloat16* __restrict__ Bt,
                                                   const float* __restrict__ bias,
                                                   void* __restrict__ Cout) {
    __shared__ __align__(16) u16 As[128 * 40];  // stride 40: 20-bank step -> only free 2-way aliasing
    __shared__ __align__(16) u16 Bs[128 * 40];
    int tid = threadIdx.x;
    int m0 = blockIdx.x * 128;
    int n0 = blockIdx.y * 128;
    int wave = tid >> 6, lane = tid & 63;
    int wm = (wave & 1) * 64, wn = (wave >> 1) * 64;
    int lm = lane & 15, quad = lane >> 4;
    int k8 = quad * 8;
    int sr = tid >> 2;          // staging row 0..63 (+64 for second half)
    int sc = (tid & 3) * 8;     // staging column octet 0,8,16,24
    const u16* Au = (const u16*)A;
    const u16* Bu = (const u16*)Bt;

    f32x4 acc[4][4];
#pragma unroll
    for (int i = 0; i < 4; i++)
#pragma unroll
        for (int j = 0; j < 4; j++) acc[i][j] = (f32x4){0.f, 0.f, 0.f, 0.f};

    uint4 ra0, ra1, rb0, rb1;
    {
        ra0 = *(const uint4*)&Au[(size_t)(m0 + sr) * K + sc];
        ra1 = *(const uint4*)&Au[(size_t)(m0 + sr + 64) * K + sc];
        rb0 = *(const uint4*)&Bu[(size_t)(n0 + sr) * K + sc];
        rb1 = *(const uint4*)&Bu[(size_t)(n0 + sr + 64) * K + sc];
    }

    for (int kt = 0; kt < K; kt += 32) {
        *(uint4*)&As[sr * 40 + sc] = ra0;
        *(uint4*)&As[(sr + 64) * 40 + sc] = ra1;
        *(uint4*)&Bs[sr * 40 + sc] = rb0;
        *(uint4*)&Bs[(sr + 64) * 40 + sc] = rb1;
        __syncthreads();
        if (kt + 32 < K) {
            int kn = kt + 32;
            ra0 = *(const uint4*)&Au[(size_t)(m0 + sr) * K + kn + sc];
            ra1 = *(const uint4*)&Au[(size_t)(m0 + sr + 64) * K + kn + sc];
            rb0 = *(const uint4*)&Bu[(size_t)(n0 + sr) * K + kn + sc];
            rb1 = *(const uint4*)&Bu[(size_t)(n0 + sr + 64) * K + kn + sc];
        }
        bf16x8 a[4], b[4];
#pragma unroll
        for (int i = 0; i < 4; i++) a[i] = *(const bf16x8*)&As[(wm + i * 16 + lm) * 40 + k8];
#pragma unroll
        for (int j = 0; j < 4; j++) b[j] = *(const bf16x8*)&Bs[(wn + j * 16 + lm) * 40 + k8];
#pragma unroll
        for (int i = 0; i < 4; i++)
#pragma unroll
            for (int j = 0; j < 4; j++)
                acc[i][j] = __builtin_amdgcn_mfma_f32_16x16x32_bf16(a[i], b[j], acc[i][j], 0, 0, 0);
        __syncthreads();
    }

#pragma unroll
    for (int i = 0; i < 4; i++) {
#pragma unroll
        for (int j = 0; j < 4; j++) {
            int n = n0 + wn + j * 16 + lm;
            float bv = bias[n];
#pragma unroll
            for (int r = 0; r < 4; r++) {
                int m = m0 + wm + i * 16 + quad * 4 + r;
                float v = acc[i][j][r] + bv;
                if (RELU) v = fmaxf(v, 0.f);
                if (OUT_BF16)
                    ((__hip_bfloat16*)Cout)[(size_t)m * HID + n] = __float2bfloat16(v);
                else
                    ((float*)Cout)[(size_t)m * HID + n] = v;
            }
        }
    }
}

// ---------------- launch ----------------

extern "C" void kernel_launch(void* const* d_in, const int* in_sizes, int n_in,
                              void* d_out, int out_size, void* d_ws, size_t ws_size,
                              hipStream_t stream) {
    const float* x   = (const float*)d_in[0];
    const int* src1  = (const int*)d_in[1];
    const int* dst1  = (const int*)d_in[2];
    const int* src2  = (const int*)d_in[3];
    const int* dst2  = (const int*)d_in[4];
    const float* W1l = (const float*)d_in[5];
    const float* b1  = (const float*)d_in[6];
    const float* W1r = (const float*)d_in[7];
    const float* W2l = (const float*)d_in[8];
    const float* b2  = (const float*)d_in[9];
    const float* W2r = (const float*)d_in[10];

    char* ws = (char*)d_ws;
    size_t off = 0;
    auto carve = [&](size_t bytes) -> char* {
        char* p = ws + off;
        off += (bytes + 255) & ~(size_t)255;
        return p;
    };
    __hip_bfloat16* A1  = (__hip_bfloat16*)carve((size_t)N1C * K1 * 2);
    __hip_bfloat16* Bt1 = (__hip_bfloat16*)carve((size_t)HID * K1 * 2);
    __hip_bfloat16* h   = (__hip_bfloat16*)carve((size_t)N1C * HID * 2);
    __hip_bfloat16* A2  = (__hip_bfloat16*)carve((size_t)N2C * K2 * 2);
    __hip_bfloat16* Bt2 = (__hip_bfloat16*)carve((size_t)HID * K2 * 2);
    int* cnt1  = (int*)carve(N1C * 4);
    int* offs1 = (int*)carve(N1C * 4);
    int* cur1  = (int*)carve(N1C * 4);
    int* eidx1 = (int*)carve((size_t)E1C * 4);
    int* cnt2  = (int*)carve(N2C * 4);
    int* offs2 = (int*)carve(N2C * 4);
    int* cur2  = (int*)carve(N2C * 4);
    int* eidx2 = (int*)carve((size_t)E2C * 4);

    zero_cnt_kernel<<<(N1C + N2C + 255) / 256, 256, 0, stream>>>(cnt1, cnt2);
    hist_kernel<<<(E1C + E2C + 255) / 256, 256, 0, stream>>>(dst1, cnt1, dst2, cnt2);
    scan_kernel<<<2, 256, 0, stream>>>(cnt1, offs1, cur1, cnt2, offs2, cur2);
    fill_kernel<<<(E1C + E2C + 255) / 256, 256, 0, stream>>>(src1, dst1, cur1, eidx1,
                                                             src2, dst2, cur2, eidx2);
    build_bt_kernel<<<(HID * K1 + HID * K2 + 255) / 256, 256, 0, stream>>>(W1l, W1r, Bt1, W2l, W2r, Bt2);
    agg1_kernel<<<N1C, 256, 0, stream>>>(x, cnt1, offs1, eidx1, (u16*)A1);
    gemm_kernel<K1, true, true><<<dim3(N1C / 128, 2), 256, 0, stream>>>(A1, Bt1, b1, h);
    agg2_kernel<<<N2C, 256, 0, stream>>>(h, cnt2, offs2, eidx2, A2);
    gemm_kernel<K2, false, false><<<dim3(N2C / 128, 2), 256, 0, stream>>>(A2, Bt2, b2, d_out);
}